// Round 1
// baseline (7556.817 us; speedup 1.0000x reference)
//
#include <hip/hip_runtime.h>
#include <stdint.h>

// ---------------------------------------------------------------------------
// Fused SDE sampler, round 3: TRANSPOSED MFMA scheme.
//   D' = W^T · act^T  -> C layout (col = obs-row, rows = neurons) matches the
//   next layer's B-fragment layout exactly:
//     - every epilogue is a packed f16x4 ds_write_b64 (no scalar b16 stores)
//     - every activation fragment is a contiguous ds_read_b128 (2-way banks)
//     - layer-3 output lands in the registers of the lane that owns those
//       state elements -> Euler-Maruyama update fused into L3 epilogue.
//   State X, X0 live in registers; sX/sX0/x0A/sO removed from LDS:
//   60.4 KB -> 41.7 KB  => 3 blocks/CU (12 waves), barriers 4 -> 3 per step.
//   RNG key chain + per-step scalars precomputed once in prep (uniform
//   s_loads in the main loop).  erfinv uses -__logf(fma(-x,x,1)) fast path.
//   ws packing of weight fragments is UNCHANGED (A-frag(row,k) layout is the
//   transpose of B-frag(k,n) layout -> same bytes).
// ---------------------------------------------------------------------------

#define PARTITIONABLE 1

namespace {

constexpr int   kObs    = 65536;
constexpr int   kDim    = 64;
constexpr int   kSteps  = 64;
constexpr float kDs     = 1.0f / 64.0f;
constexpr float kSqrtDs = 0.125f;

constexpr int kWeightBytes = 224 * 1024;          // 224 fragment tiles
constexpr int kKeysOff     = kWeightBytes;        // uint32[2][64][2] = 1 KB
constexpr int kStabOff     = kKeysOff + 1024;     // f32x4[64]        = 1 KB

typedef _Float16 f16x8 __attribute__((ext_vector_type(8)));
typedef _Float16 f16x4 __attribute__((ext_vector_type(4)));
typedef float    f32x4 __attribute__((ext_vector_type(4)));

#define MFMA16(a, b, c) __builtin_amdgcn_mfma_f32_16x16x32_f16((a), (b), (c), 0, 0, 0)

__device__ __forceinline__ uint32_t rotl(uint32_t v, int r) {
  return (v << r) | (v >> (32 - r));
}

__device__ __forceinline__ void tf2x32(uint32_t k0, uint32_t k1,
                                       uint32_t& x0, uint32_t& x1) {
  uint32_t k2 = k0 ^ k1 ^ 0x1BD11BDAu;
  x0 += k0; x1 += k1;
  x0 += x1; x1 = rotl(x1, 13); x1 ^= x0;
  x0 += x1; x1 = rotl(x1, 15); x1 ^= x0;
  x0 += x1; x1 = rotl(x1, 26); x1 ^= x0;
  x0 += x1; x1 = rotl(x1,  6); x1 ^= x0;
  x0 += k1; x1 += k2 + 1u;
  x0 += x1; x1 = rotl(x1, 17); x1 ^= x0;
  x0 += x1; x1 = rotl(x1, 29); x1 ^= x0;
  x0 += x1; x1 = rotl(x1, 16); x1 ^= x0;
  x0 += x1; x1 = rotl(x1, 24); x1 ^= x0;
  x0 += k2; x1 += k0 + 2u;
  x0 += x1; x1 = rotl(x1, 13); x1 ^= x0;
  x0 += x1; x1 = rotl(x1, 15); x1 ^= x0;
  x0 += x1; x1 = rotl(x1, 26); x1 ^= x0;
  x0 += x1; x1 = rotl(x1,  6); x1 ^= x0;
  x0 += k0; x1 += k1 + 3u;
  x0 += x1; x1 = rotl(x1, 17); x1 ^= x0;
  x0 += x1; x1 = rotl(x1, 29); x1 ^= x0;
  x0 += x1; x1 = rotl(x1, 16); x1 ^= x0;
  x0 += x1; x1 = rotl(x1, 24); x1 ^= x0;
  x0 += k1; x1 += k2 + 4u;
  x0 += x1; x1 = rotl(x1, 13); x1 ^= x0;
  x0 += x1; x1 = rotl(x1, 15); x1 ^= x0;
  x0 += x1; x1 = rotl(x1, 26); x1 ^= x0;
  x0 += x1; x1 = rotl(x1,  6); x1 ^= x0;
  x0 += k2; x1 += k0 + 5u;
}

__device__ __forceinline__ void jax_split(uint32_t k0, uint32_t k1,
                                          uint32_t& a0, uint32_t& a1,
                                          uint32_t& b0, uint32_t& b1) {
#if PARTITIONABLE
  uint32_t x0 = 0u, x1 = 0u; tf2x32(k0, k1, x0, x1); a0 = x0; a1 = x1;
  uint32_t y0 = 0u, y1 = 1u; tf2x32(k0, k1, y0, y1); b0 = y0; b1 = y1;
#else
  uint32_t x0 = 0u, x1 = 2u; tf2x32(k0, k1, x0, x1);
  uint32_t y0 = 1u, y1 = 3u; tf2x32(k0, k1, y0, y1);
  a0 = x0; a1 = y0; b0 = x1; b1 = y1;
#endif
}

__device__ __forceinline__ uint32_t draw_bits(uint32_t k0, uint32_t k1, uint32_t i) {
#if PARTITIONABLE
  uint32_t x0 = 0u, x1 = i;
  tf2x32(k0, k1, x0, x1);
  return x0 ^ x1;
#else
  const uint32_t half = (uint32_t)kObs * kDim / 2;
  if (i < half) {
    uint32_t x0 = i, x1 = i + half; tf2x32(k0, k1, x0, x1); return x0;
  } else {
    uint32_t x0 = i - half, x1 = i; tf2x32(k0, k1, x0, x1); return x1;
  }
#endif
}

__device__ __forceinline__ float erfinv32(float x) {
  // fast path: w = -ln(1-x^2) via single-rounded fma + v_log_f32
  float w = -__logf(fmaf(-x, x, 1.0f));
  float p;
  if (w < 5.0f) {
    w = w - 2.5f;
    p =            2.81022636e-08f;
    p = fmaf(p, w, 3.43273939e-07f);
    p = fmaf(p, w, -3.5233877e-06f);
    p = fmaf(p, w, -4.39150654e-06f);
    p = fmaf(p, w, 0.00021858087f);
    p = fmaf(p, w, -0.00125372503f);
    p = fmaf(p, w, -0.00417768164f);
    p = fmaf(p, w, 0.246640727f);
    p = fmaf(p, w, 1.50140941f);
  } else {
    w = sqrtf(w) - 3.0f;
    p =            -0.000200214257f;
    p = fmaf(p, w, 0.000100950558f);
    p = fmaf(p, w, 0.00134934322f);
    p = fmaf(p, w, -0.00367342844f);
    p = fmaf(p, w, 0.00573950773f);
    p = fmaf(p, w, -0.0076224613f);
    p = fmaf(p, w, 0.00943887047f);
    p = fmaf(p, w, 1.00167406f);
    p = fmaf(p, w, 2.83297682f);
  }
  return p * x;
}

__device__ __forceinline__ float bits_to_normal(uint32_t bits) {
  const float lo = -0.99999994f;
  float f = __uint_as_float(0x3f800000u | (bits >> 9)) - 1.0f;
  float u = fmaxf(lo, fmaf(f, 2.0f, lo));
  return 1.41421356237f * erfinv32(u);
}

}  // namespace

// ---------------------------------------------------------------------------
// Weight prep (fragment packing UNCHANGED) + RNG key / step-scalar tables.
// Fragment tile = 16 x 32, 1024 B; lane l holds W[k=(l>>4)*8+j][n = l&15]
// which is simultaneously the A'-fragment of W^T (row = neuron = l&15).
//   L1 : tiles [  0, 64) : id =       w*16 + mt*4 + kt   (K=128: x|x0 rows of W1)
//   L2 : tiles [ 64,192) : id =  64 + w*32 + mt*8 + kt
//   L3 : tiles [192,224) : id = 192 + w*8  + kt          (mtile == w)
// Block 224: thread 0/1 compute the per-sample draw-key chains; threads
// 0..63 compute per-step scalars {s, A, coef}.
// ---------------------------------------------------------------------------
__global__ void prep_weights(const float* __restrict__ W1,
                             const float* __restrict__ W2,
                             const float* __restrict__ W3,
                             _Float16* __restrict__ ws) {
  const int tile = blockIdx.x;
  const int t    = threadIdx.x;

  if (tile >= 224) {
    // ---- RNG key chains (2 samples) ----
    if (t < 2) {
      uint32_t* kout = (uint32_t*)((char*)ws + kKeysOff) + t * 128;
      uint32_t s0a, s0b, s1a, s1b;
      jax_split(0u, 1u, s0a, s0b, s1a, s1b);
      const uint32_t sk0 = t ? s1a : s0a;
      const uint32_t sk1 = t ? s1b : s0b;
      uint32_t kd0, kd1, kl0, kl1;
      jax_split(sk0, sk1, kd0, kd1, kl0, kl1);
      kout[0] = kd0; kout[1] = kd1;
      for (int n = 1; n < kSteps; ++n) {
        uint32_t na, nb, xa, xb;
        jax_split(kl0, kl1, na, nb, xa, xb);
        kl0 = na; kl1 = nb;
        kout[2 * n] = xa; kout[2 * n + 1] = xb;
      }
    }
    // ---- per-step scalars ----
    if (t < kSteps) {
      const float s  = (float)t * kDs;
      const float sg = 1.0f - s;
      f32x4 v;
      v[0] = s;
      v[1] = (t == 0) ? 0.0f : 1.0f / (s * sg);
      v[2] = 0.5f * (1.0f - sg * sg);
      v[3] = 0.0f;
      *(f32x4*)((char*)ws + kStabOff + t * 16) = v;
    }
    return;
  }

  const int lane = t >> 2;
  const int j0   = (t & 3) * 2;

  int layer, w, nt, kt;
  if (tile < 64)       { layer = 1; w = tile >> 4;      nt = (tile >> 2) & 3; kt = tile & 3; }
  else if (tile < 192) { int u = tile - 64;  layer = 2; w = u >> 5; nt = (u >> 3) & 3; kt = u & 7; }
  else                 { int u = tile - 192; layer = 3; w = u >> 3; nt = 0;           kt = u & 7; }

  const int col = (layer == 3) ? (w * 16 + (lane & 15))
                               : ((w * 4 + nt) * 16 + (lane & 15));
#pragma unroll
  for (int jj = 0; jj < 2; ++jj) {
    const int j = j0 + jj;
    const int k = kt * 32 + ((lane >> 4) << 3) + j;
    float v;
    if (layer == 1)      v = W1[k * 256 + col];   // rows 0..127 of W1 (x|x0)
    else if (layer == 2) v = W2[k * 256 + col];
    else                 v = W3[k * 64  + col];
    ws[(size_t)tile * 512 + lane * 8 + j] = (_Float16)v;
  }
}

// ---------------------------------------------------------------------------
// Main fused kernel (transposed MFMA, fused update).
// ---------------------------------------------------------------------------
__global__ __launch_bounds__(256, 3)
void sde_mfma(const float* __restrict__ X0g,
              const float* __restrict__ W1,
              const float* __restrict__ b1,
              const float* __restrict__ b2,
              const float* __restrict__ b3,
              const _Float16* __restrict__ ws,
              float* __restrict__ out) {
  // LDS: 4.5K + 16.5K*2 + 3.3K = 41.7 KB -> 3 blocks/CU.
  __shared__ alignas(16) _Float16 xA[32][72];     // f16 state, [obsrow][dim]
  __shared__ alignas(16) _Float16 h1[32][264];    // [obsrow][neuron]
  __shared__ alignas(16) _Float16 h2[32][264];
  __shared__ alignas(16) float    bb[832];        // b1|W1s|b2 (256 ea) | b3 (64)

  const int t  = threadIdx.x;
  const int w  = t >> 6;          // wave id: owns neurons [64w, 64w+64)
  const int l  = t & 63;
  const int lq = l >> 4;          // quad
  const int lm = l & 15;
  const int samp = blockIdx.x >> 11;       // 2048 blocks per sample
  const int tile = blockIdx.x & 2047;
  const int r0   = tile * 32;
  const int colq = w * 16 + lq * 4;        // this lane's 4 state dims

  // ---- stage biases + s-row of W1 into LDS ----
  bb[t]       = b1[t];
  bb[256 + t] = W1[128 * 256 + t];
  bb[512 + t] = b2[t];
  if (t < 64) bb[768 + t] = b3[t];

  // ---- per-lane state + X0 fragments (registers, no LDS) ----
  float xv[2][4];     // X state: (obsrow nt*16+lm, dims colq..colq+3)
  f32x4 x0q[2];       // X0 f32 for the score term
  f16x8 x0B[2][2];    // X0 B-fragments for layer 1 (static all steps)
#pragma unroll
  for (int nt = 0; nt < 2; ++nt) {
    const float* pr = X0g + (size_t)(r0 + nt * 16 + lm) * kDim;
    x0q[nt] = *(const f32x4*)(pr + colq);
#pragma unroll
    for (int k2 = 0; k2 < 2; ++k2) {
      const f32x4 a = *(const f32x4*)(pr + k2 * 32 + lq * 8);
      const f32x4 b = *(const f32x4*)(pr + k2 * 32 + lq * 8 + 4);
      f16x8 h;
      h[0] = (_Float16)a[0]; h[1] = (_Float16)a[1];
      h[2] = (_Float16)a[2]; h[3] = (_Float16)a[3];
      h[4] = (_Float16)b[0]; h[5] = (_Float16)b[1];
      h[6] = (_Float16)b[2]; h[7] = (_Float16)b[3];
      x0B[nt][k2] = h;
    }
    f16x4 hx;
#pragma unroll
    for (int q = 0; q < 4; ++q) {
      xv[nt][q] = x0q[nt][q];
      hx[q] = (_Float16)x0q[nt][q];
    }
    *(f16x4*)&xA[nt * 16 + lm][colq] = hx;
  }

  // ---- fragment base pointers / tables ----
  const char* wsB = (const char*)ws;
  const char* pA1 = wsB + (size_t)w * 16 * 1024;
  const char* pA2 = wsB + 64 * 1024  + (size_t)w * 32 * 1024;
  const char* pA3 = wsB + 192 * 1024 + (size_t)w * 8 * 1024;
  const int lb = l * 16;
  const uint32_t* keys = (const uint32_t*)(wsB + kKeysOff) + samp * 128;
  const f32x4*    stab = (const f32x4*)(wsB + kStabOff);

  __syncthreads();

  for (int n = 0; n < kSteps; ++n) {
    const f32x4 st = stab[n];
    const float s = st[0], A = st[1], coef = st[2];
    const uint32_t ka = keys[2 * n], kb = keys[2 * n + 1];

    // ================= layer 1 (M=256 neurons, N=32 rows, K=128) =========
    f16x8 bx[2][2];
#pragma unroll
    for (int nt = 0; nt < 2; ++nt)
#pragma unroll
      for (int kt = 0; kt < 2; ++kt)
        bx[nt][kt] = *(const f16x8*)&xA[nt * 16 + lm][kt * 32 + lq * 8];
#pragma unroll
    for (int mt = 0; mt < 4; ++mt) {
      f32x4 c0 = {0.f, 0.f, 0.f, 0.f}, c1 = {0.f, 0.f, 0.f, 0.f};
#pragma unroll
      for (int kt = 0; kt < 4; ++kt) {
        const f16x8 aW = *(const f16x8*)(pA1 + (mt * 4 + kt) * 1024 + lb);
        const f16x8 bf0 = (kt < 2) ? bx[0][kt] : x0B[0][kt - 2];
        const f16x8 bf1 = (kt < 2) ? bx[1][kt] : x0B[1][kt - 2];
        c0 = MFMA16(aW, bf0, c0);
        c1 = MFMA16(aW, bf1, c1);
      }
      const int nb = (w * 4 + mt) * 16 + lq * 4;
      const f32x4 bq = *(const f32x4*)&bb[nb];
      const f32x4 wq = *(const f32x4*)&bb[256 + nb];
      f16x4 o0, o1;
#pragma unroll
      for (int q = 0; q < 4; ++q) {
        const float be = fmaf(s, wq[q], bq[q]);
        o0[q] = (_Float16)fmaxf(c0[q] + be, 0.f);
        o1[q] = (_Float16)fmaxf(c1[q] + be, 0.f);
      }
      *(f16x4*)&h1[lm][nb]      = o0;
      *(f16x4*)&h1[16 + lm][nb] = o1;
    }
    __syncthreads();

    // ================= layer 2 (M=256, N=32, K=256) ======================
    f32x4 c[4][2];
#pragma unroll
    for (int mt = 0; mt < 4; ++mt)
#pragma unroll
      for (int nt = 0; nt < 2; ++nt)
        c[mt][nt] = (f32x4){0.f, 0.f, 0.f, 0.f};
#pragma unroll
    for (int half = 0; half < 2; ++half) {
      f16x8 bh[2][4];
#pragma unroll
      for (int nt = 0; nt < 2; ++nt)
#pragma unroll
        for (int k4 = 0; k4 < 4; ++k4)
          bh[nt][k4] = *(const f16x8*)&h1[nt * 16 + lm][(half * 4 + k4) * 32 + lq * 8];
#pragma unroll
      for (int mt = 0; mt < 4; ++mt)
#pragma unroll
        for (int k4 = 0; k4 < 4; ++k4) {
          const f16x8 aW = *(const f16x8*)(pA2 + (mt * 8 + half * 4 + k4) * 1024 + lb);
          c[mt][0] = MFMA16(aW, bh[0][k4], c[mt][0]);
          c[mt][1] = MFMA16(aW, bh[1][k4], c[mt][1]);
        }
    }
#pragma unroll
    for (int mt = 0; mt < 4; ++mt) {
      const int nb = (w * 4 + mt) * 16 + lq * 4;
      const f32x4 bq = *(const f32x4*)&bb[512 + nb];
      f16x4 o0, o1;
#pragma unroll
      for (int q = 0; q < 4; ++q) {
        o0[q] = (_Float16)fmaxf(c[mt][0][q] + bq[q], 0.f);
        o1[q] = (_Float16)fmaxf(c[mt][1][q] + bq[q], 0.f);
      }
      *(f16x4*)&h2[lm][nb]      = o0;
      *(f16x4*)&h2[16 + lm][nb] = o1;
    }
    __syncthreads();

    // ======== layer 3 (M=64, N=32, K=256; wave w -> dims [16w,16w+16)) ====
    f32x4 d0 = {0.f, 0.f, 0.f, 0.f}, d1 = {0.f, 0.f, 0.f, 0.f};
#pragma unroll
    for (int half = 0; half < 2; ++half) {
      f16x8 bh[2][4];
#pragma unroll
      for (int nt = 0; nt < 2; ++nt)
#pragma unroll
        for (int k4 = 0; k4 < 4; ++k4)
          bh[nt][k4] = *(const f16x8*)&h2[nt * 16 + lm][(half * 4 + k4) * 32 + lq * 8];
#pragma unroll
      for (int k4 = 0; k4 < 4; ++k4) {
        const f16x8 aW = *(const f16x8*)(pA3 + (half * 4 + k4) * 1024 + lb);
        d0 = MFMA16(aW, bh[0][k4], d0);
        d1 = MFMA16(aW, bh[1][k4], d1);
      }
    }

    // ================= fused Euler-Maruyama update (in registers) ========
    const f32x4 b3q = *(const f32x4*)&bb[768 + colq];
#pragma unroll
    for (int nt = 0; nt < 2; ++nt) {
      const uint32_t gi0 = (uint32_t)((r0 + nt * 16 + lm) * kDim + colq);
      f16x4 hx;
#pragma unroll
      for (int q = 0; q < 4; ++q) {
        const float ov    = (nt ? d1[q] : d0[q]) + b3q[q];
        const float eta   = bits_to_normal(draw_bits(ka, kb, gi0 + q));
        const float score = A * (s * ov - (xv[nt][q] - x0q[nt][q]));
        const float nx    = xv[nt][q] + kDs * (ov + coef * score) + kSqrtDs * eta;
        xv[nt][q] = nx;
        hx[q] = (_Float16)nx;
      }
      *(f16x4*)&xA[nt * 16 + lm][colq] = hx;
    }
    __syncthreads();
  }

  // ---- write result (each lane owns its 8 elements) ----
#pragma unroll
  for (int nt = 0; nt < 2; ++nt) {
    const size_t ob = (size_t)samp * ((size_t)kObs * kDim) +
                      (size_t)(r0 + nt * 16 + lm) * kDim + colq;
    f32x4 v;
#pragma unroll
    for (int q = 0; q < 4; ++q) v[q] = xv[nt][q];
    *(f32x4*)(out + ob) = v;
  }
}

extern "C" void kernel_launch(void* const* d_in, const int* in_sizes, int n_in,
                              void* d_out, int out_size, void* d_ws, size_t ws_size,
                              hipStream_t stream) {
  const float* X0 = (const float*)d_in[0];
  const float* W1 = (const float*)d_in[1];
  const float* b1 = (const float*)d_in[2];
  const float* W2 = (const float*)d_in[3];
  const float* b2 = (const float*)d_in[4];
  const float* W3 = (const float*)d_in[5];
  const float* b3 = (const float*)d_in[6];
  _Float16* ws = (_Float16*)d_ws;   // 224 KB fragments + 2 KB key/scalar tables

  prep_weights<<<dim3(225), dim3(256), 0, stream>>>(W1, W2, W3, ws);
  sde_mfma<<<dim3(4096), dim3(256), 0, stream>>>(X0, W1, b1, b2, b3, ws,
                                                 (float*)d_out);
}

// Round 2
// 3076.467 us; speedup vs baseline: 2.4563x; 2.4563x over previous
//
#include <hip/hip_runtime.h>
#include <stdint.h>

// ---------------------------------------------------------------------------
// Fused SDE sampler, round 4: WEIGHTS IN REGISTERS.
//   Round-3 regression diagnosis: FETCH_SIZE 27 GB (weight fragments re-read
//   from global every step, ~50% L2 miss) -> MFMA A-operand loads latency-
//   bound at 8.5 waves/CU.  Fix: re-partition to 8 waves x 32 neurons so the
//   per-wave weight slice is 32 KB = 128 VGPR, preloaded ONCE per block.
//   Step loop is 100% on-chip: ds_read activations -> reg MFMA -> VALU RNG.
//   - Block: 512 thr / 8 waves, 64 obs rows, 1 block/CU (VGPR-bound, 2 w/SIMD)
//   - L1: M=32(neurons/wave) N=64 K=128 ; L2: M=32 N=64 K=256
//   - L3: wave w -> dim-tile w>>1, row-tiles {2(w&1), 2(w&1)+1}; update fused,
//     each thread owns 8 state elems (xv/x0q in regs), 8 threefry draws.
//   - Fragment packing identical to round 3 (verified), just re-partitioned:
//     per-wave 32 contiguous 1KB tiles [L1 2mtx4kt | L2 2mtx8kt | L3 8kt].
//   - RNG key chain + per-step scalars still precomputed in prep (ws tables).
// ---------------------------------------------------------------------------

#define PARTITIONABLE 1

namespace {

constexpr int   kObs    = 65536;
constexpr int   kDim    = 64;
constexpr int   kSteps  = 64;
constexpr float kDs     = 1.0f / 64.0f;
constexpr float kSqrtDs = 0.125f;

constexpr int kWeightBytes = 256 * 1024;          // 8 waves x 32 tiles x 1 KB
constexpr int kKeysOff     = kWeightBytes;        // uint32[2][64][2] = 1 KB
constexpr int kStabOff     = kKeysOff + 1024;     // f32x4[64]        = 1 KB

typedef _Float16 f16x8 __attribute__((ext_vector_type(8)));
typedef _Float16 f16x4 __attribute__((ext_vector_type(4)));
typedef float    f32x4 __attribute__((ext_vector_type(4)));

#define MFMA16(a, b, c) __builtin_amdgcn_mfma_f32_16x16x32_f16((a), (b), (c), 0, 0, 0)

__device__ __forceinline__ uint32_t rotl(uint32_t v, int r) {
  return (v << r) | (v >> (32 - r));
}

__device__ __forceinline__ void tf2x32(uint32_t k0, uint32_t k1,
                                       uint32_t& x0, uint32_t& x1) {
  uint32_t k2 = k0 ^ k1 ^ 0x1BD11BDAu;
  x0 += k0; x1 += k1;
  x0 += x1; x1 = rotl(x1, 13); x1 ^= x0;
  x0 += x1; x1 = rotl(x1, 15); x1 ^= x0;
  x0 += x1; x1 = rotl(x1, 26); x1 ^= x0;
  x0 += x1; x1 = rotl(x1,  6); x1 ^= x0;
  x0 += k1; x1 += k2 + 1u;
  x0 += x1; x1 = rotl(x1, 17); x1 ^= x0;
  x0 += x1; x1 = rotl(x1, 29); x1 ^= x0;
  x0 += x1; x1 = rotl(x1, 16); x1 ^= x0;
  x0 += x1; x1 = rotl(x1, 24); x1 ^= x0;
  x0 += k2; x1 += k0 + 2u;
  x0 += x1; x1 = rotl(x1, 13); x1 ^= x0;
  x0 += x1; x1 = rotl(x1, 15); x1 ^= x0;
  x0 += x1; x1 = rotl(x1, 26); x1 ^= x0;
  x0 += x1; x1 = rotl(x1,  6); x1 ^= x0;
  x0 += k0; x1 += k1 + 3u;
  x0 += x1; x1 = rotl(x1, 17); x1 ^= x0;
  x0 += x1; x1 = rotl(x1, 29); x1 ^= x0;
  x0 += x1; x1 = rotl(x1, 16); x1 ^= x0;
  x0 += x1; x1 = rotl(x1, 24); x1 ^= x0;
  x0 += k1; x1 += k2 + 4u;
  x0 += x1; x1 = rotl(x1, 13); x1 ^= x0;
  x0 += x1; x1 = rotl(x1, 15); x1 ^= x0;
  x0 += x1; x1 = rotl(x1, 26); x1 ^= x0;
  x0 += x1; x1 = rotl(x1,  6); x1 ^= x0;
  x0 += k2; x1 += k0 + 5u;
}

__device__ __forceinline__ void jax_split(uint32_t k0, uint32_t k1,
                                          uint32_t& a0, uint32_t& a1,
                                          uint32_t& b0, uint32_t& b1) {
#if PARTITIONABLE
  uint32_t x0 = 0u, x1 = 0u; tf2x32(k0, k1, x0, x1); a0 = x0; a1 = x1;
  uint32_t y0 = 0u, y1 = 1u; tf2x32(k0, k1, y0, y1); b0 = y0; b1 = y1;
#else
  uint32_t x0 = 0u, x1 = 2u; tf2x32(k0, k1, x0, x1);
  uint32_t y0 = 1u, y1 = 3u; tf2x32(k0, k1, y0, y1);
  a0 = x0; a1 = y0; b0 = x1; b1 = y1;
#endif
}

__device__ __forceinline__ uint32_t draw_bits(uint32_t k0, uint32_t k1, uint32_t i) {
#if PARTITIONABLE
  uint32_t x0 = 0u, x1 = i;
  tf2x32(k0, k1, x0, x1);
  return x0 ^ x1;
#else
  const uint32_t half = (uint32_t)kObs * kDim / 2;
  if (i < half) {
    uint32_t x0 = i, x1 = i + half; tf2x32(k0, k1, x0, x1); return x0;
  } else {
    uint32_t x0 = i - half, x1 = i; tf2x32(k0, k1, x0, x1); return x1;
  }
#endif
}

__device__ __forceinline__ float erfinv32(float x) {
  float w = -__logf(fmaf(-x, x, 1.0f));
  float p;
  if (w < 5.0f) {
    w = w - 2.5f;
    p =            2.81022636e-08f;
    p = fmaf(p, w, 3.43273939e-07f);
    p = fmaf(p, w, -3.5233877e-06f);
    p = fmaf(p, w, -4.39150654e-06f);
    p = fmaf(p, w, 0.00021858087f);
    p = fmaf(p, w, -0.00125372503f);
    p = fmaf(p, w, -0.00417768164f);
    p = fmaf(p, w, 0.246640727f);
    p = fmaf(p, w, 1.50140941f);
  } else {
    w = sqrtf(w) - 3.0f;
    p =            -0.000200214257f;
    p = fmaf(p, w, 0.000100950558f);
    p = fmaf(p, w, 0.00134934322f);
    p = fmaf(p, w, -0.00367342844f);
    p = fmaf(p, w, 0.00573950773f);
    p = fmaf(p, w, -0.0076224613f);
    p = fmaf(p, w, 0.00943887047f);
    p = fmaf(p, w, 1.00167406f);
    p = fmaf(p, w, 2.83297682f);
  }
  return p * x;
}

__device__ __forceinline__ float bits_to_normal(uint32_t bits) {
  const float lo = -0.99999994f;
  float f = __uint_as_float(0x3f800000u | (bits >> 9)) - 1.0f;
  float u = fmaxf(lo, fmaf(f, 2.0f, lo));
  return 1.41421356237f * erfinv32(u);
}

}  // namespace

// ---------------------------------------------------------------------------
// Weight prep: per-wave contiguous fragment tiles + RNG/step tables.
// Tile = 16(M) x 32(K), 1024 B; lane l holds W[k=(l>>4)*8+j][m=l&15]
// (the A-fragment of W^T).  Global tile id G = w*32 + T, w in [0,8):
//   T in [ 0, 8) : L1, mt=T>>2, kt=T&3   neurons w*32+mt*16, k=kt*32 (x|x0)
//   T in [ 8,24) : L2, u=T-8, mt=u>>3, kt=u&7
//   T in [24,32) : L3, kt=T-24, dim-tile = w>>1
// Block 256: thread 0/1 per-sample key chains; threads 0..63 step scalars.
// ---------------------------------------------------------------------------
__global__ void prep_weights(const float* __restrict__ W1,
                             const float* __restrict__ W2,
                             const float* __restrict__ W3,
                             _Float16* __restrict__ ws) {
  const int G = blockIdx.x;
  const int t = threadIdx.x;

  if (G >= 256) {
    if (t < 2) {
      uint32_t* kout = (uint32_t*)((char*)ws + kKeysOff) + t * 128;
      uint32_t s0a, s0b, s1a, s1b;
      jax_split(0u, 1u, s0a, s0b, s1a, s1b);
      const uint32_t sk0 = t ? s1a : s0a;
      const uint32_t sk1 = t ? s1b : s0b;
      uint32_t kd0, kd1, kl0, kl1;
      jax_split(sk0, sk1, kd0, kd1, kl0, kl1);
      kout[0] = kd0; kout[1] = kd1;
      for (int n = 1; n < kSteps; ++n) {
        uint32_t na, nb, xa, xb;
        jax_split(kl0, kl1, na, nb, xa, xb);
        kl0 = na; kl1 = nb;
        kout[2 * n] = xa; kout[2 * n + 1] = xb;
      }
    }
    if (t < kSteps) {
      const float s  = (float)t * kDs;
      const float sg = 1.0f - s;
      f32x4 v;
      v[0] = s;
      v[1] = (t == 0) ? 0.0f : 1.0f / (s * sg);
      v[2] = 0.5f * (1.0f - sg * sg);
      v[3] = 0.0f;
      *(f32x4*)((char*)ws + kStabOff + t * 16) = v;
    }
    return;
  }

  const int lane = t >> 2;
  const int j0   = (t & 3) * 2;
  const int w    = G >> 5;
  const int T    = G & 31;
  const int lm   = lane & 15;
  const int kb   = (lane >> 4) << 3;

#pragma unroll
  for (int jj = 0; jj < 2; ++jj) {
    const int j = j0 + jj;
    float v;
    if (T < 8) {
      const int mt = T >> 2, kt = T & 3;
      const int col = w * 32 + mt * 16 + lm;
      const int k   = kt * 32 + kb + j;          // 0..127 : [x | x0] rows of W1
      v = W1[k * 256 + col];
    } else if (T < 24) {
      const int u = T - 8;
      const int mt = u >> 3, kt = u & 7;
      const int col = w * 32 + mt * 16 + lm;
      const int k   = kt * 32 + kb + j;
      v = W2[k * 256 + col];
    } else {
      const int kt  = T - 24;
      const int col = (w >> 1) * 16 + lm;        // L3 dim-tile = w>>1
      const int k   = kt * 32 + kb + j;
      v = W3[k * 64 + col];
    }
    ws[(size_t)G * 512 + lane * 8 + j] = (_Float16)v;
  }
}

// ---------------------------------------------------------------------------
// Main fused kernel: register-resident weights, on-chip step loop.
// ---------------------------------------------------------------------------
__global__ __launch_bounds__(512, 2)
void sde_mfma(const float* __restrict__ X0g,
              const float* __restrict__ W1,
              const float* __restrict__ b1,
              const float* __restrict__ b2,
              const float* __restrict__ b3,
              const _Float16* __restrict__ ws,
              float* __restrict__ out) {
  // LDS: 9 + 9 + 33 + 33 + 3.3 = 87.3 KB -> 1 block/CU (VGPR-bound anyway).
  __shared__ alignas(16) _Float16 xA [64][72];    // f16 state  [row][dim]
  __shared__ alignas(16) _Float16 x0A[64][72];    // f16 X0     [row][dim]
  __shared__ alignas(16) _Float16 h1 [64][264];   // [row][neuron]
  __shared__ alignas(16) _Float16 h2 [64][264];
  __shared__ alignas(16) float    bb [832];       // b1|W1s|b2 (256 ea) | b3(64)

  const int t    = threadIdx.x;
  const int w    = t >> 6;                 // wave 0..7: neurons [32w,32w+32)
  const int l    = t & 63;
  const int lq   = l >> 4;
  const int lm   = l & 15;
  const int samp = blockIdx.x >> 10;       // 1024 blocks per sample
  const int tile = blockIdx.x & 1023;
  const int r0   = tile * 64;
  const int mt3  = w >> 1;                 // L3 dim-tile
  const int ntb  = (w & 1) * 2;            // L3 row-tile base (2 tiles)
  const int d0   = mt3 * 16 + lq * 4;      // this lane's 4 dims

  // ---- stage biases + s-row of W1 ----
  if (t < 256) {
    bb[t]       = b1[t];
    bb[256 + t] = W1[128 * 256 + t];
    bb[512 + t] = b2[t];
  } else if (t < 320) {
    bb[768 + (t - 256)] = b3[t - 256];
  }

  // ---- stage X0 tile (f16) : 64 rows x 64 dims, 8 elems/thread ----
  {
    const int li = t >> 3;
    const int ci = (t & 7) * 8;
    const float* p = X0g + (size_t)(r0 + li) * kDim + ci;
    const float4 a = *(const float4*)p;
    const float4 b = *(const float4*)(p + 4);
    f16x8 h;
    h[0] = (_Float16)a.x; h[1] = (_Float16)a.y;
    h[2] = (_Float16)a.z; h[3] = (_Float16)a.w;
    h[4] = (_Float16)b.x; h[5] = (_Float16)b.y;
    h[6] = (_Float16)b.z; h[7] = (_Float16)b.w;
    *(f16x8*)&xA [li][ci] = h;
    *(f16x8*)&x0A[li][ci] = h;
  }

  // ---- own state (f32, registers): rows (ntb+ni)*16+lm, dims d0..d0+3 ----
  float xv[2][4];
  f32x4 x0q[2];
#pragma unroll
  for (int ni = 0; ni < 2; ++ni) {
    const int row = (ntb + ni) * 16 + lm;
    x0q[ni] = *(const f32x4*)(X0g + (size_t)(r0 + row) * kDim + d0);
#pragma unroll
    for (int q = 0; q < 4; ++q) xv[ni][q] = x0q[ni][q];
  }

  // ---- preload this wave's 32 KB of weight fragments into 128 VGPRs ----
  f16x8 wreg[32];
  {
    const char* pW = (const char*)ws + (size_t)w * 32768 + l * 16;
#pragma unroll
    for (int i = 0; i < 32; ++i)
      wreg[i] = *(const f16x8*)(pW + i * 1024);
  }

  const uint32_t* keys = (const uint32_t*)((const char*)ws + kKeysOff) + samp * 128;
  const f32x4*    stab = (const f32x4*)((const char*)ws + kStabOff);

  __syncthreads();

  for (int n = 0; n < kSteps; ++n) {
    const f32x4 st = stab[n];
    const float s = st[0], A = st[1], coef = st[2];
    const uint32_t ka = keys[2 * n], kbk = keys[2 * n + 1];

    // ========== layer 1: M=32 (wave's neurons), N=64, K=128 ==========
#pragma unroll
    for (int nt = 0; nt < 4; ++nt) {
      const int row = nt * 16 + lm;
      f16x8 bf[4];
      bf[0] = *(const f16x8*)&xA [row][lq * 8];
      bf[1] = *(const f16x8*)&xA [row][32 + lq * 8];
      bf[2] = *(const f16x8*)&x0A[row][lq * 8];
      bf[3] = *(const f16x8*)&x0A[row][32 + lq * 8];
#pragma unroll
      for (int mt = 0; mt < 2; ++mt) {
        f32x4 c = {0.f, 0.f, 0.f, 0.f};
#pragma unroll
        for (int kt = 0; kt < 4; ++kt)
          c = MFMA16(wreg[mt * 4 + kt], bf[kt], c);
        const int nb = w * 32 + mt * 16 + lq * 4;
        const f32x4 bq = *(const f32x4*)&bb[nb];
        const f32x4 wq = *(const f32x4*)&bb[256 + nb];
        f16x4 o;
#pragma unroll
        for (int q = 0; q < 4; ++q)
          o[q] = (_Float16)fmaxf(c[q] + fmaf(s, wq[q], bq[q]), 0.f);
        *(f16x4*)&h1[row][nb] = o;
      }
    }
    __syncthreads();

    // ========== layer 2: M=32, N=64, K=256 ==========
#pragma unroll
    for (int ntp = 0; ntp < 2; ++ntp) {
      f32x4 c[2][2];
#pragma unroll
      for (int mt = 0; mt < 2; ++mt)
#pragma unroll
        for (int ni = 0; ni < 2; ++ni)
          c[mt][ni] = (f32x4){0.f, 0.f, 0.f, 0.f};
#pragma unroll
      for (int half = 0; half < 2; ++half) {
        f16x8 bh[2][4];
#pragma unroll
        for (int ni = 0; ni < 2; ++ni)
#pragma unroll
          for (int k4 = 0; k4 < 4; ++k4)
            bh[ni][k4] = *(const f16x8*)
                &h1[(ntp * 2 + ni) * 16 + lm][(half * 4 + k4) * 32 + lq * 8];
#pragma unroll
        for (int mt = 0; mt < 2; ++mt)
#pragma unroll
          for (int k4 = 0; k4 < 4; ++k4) {
            const f16x8 aW = wreg[8 + mt * 8 + half * 4 + k4];
            c[mt][0] = MFMA16(aW, bh[0][k4], c[mt][0]);
            c[mt][1] = MFMA16(aW, bh[1][k4], c[mt][1]);
          }
      }
#pragma unroll
      for (int mt = 0; mt < 2; ++mt) {
        const int nb = w * 32 + mt * 16 + lq * 4;
        const f32x4 bq = *(const f32x4*)&bb[512 + nb];
#pragma unroll
        for (int ni = 0; ni < 2; ++ni) {
          f16x4 o;
#pragma unroll
          for (int q = 0; q < 4; ++q)
            o[q] = (_Float16)fmaxf(c[mt][ni][q] + bq[q], 0.f);
          *(f16x4*)&h2[(ntp * 2 + ni) * 16 + lm][nb] = o;
        }
      }
    }
    __syncthreads();

    // ========== layer 3 (dims [16*mt3,..+16)) + fused update ==========
    const f32x4 b3q = *(const f32x4*)&bb[768 + d0];
#pragma unroll
    for (int ni = 0; ni < 2; ++ni) {
      const int row = (ntb + ni) * 16 + lm;
      f32x4 dA = {0.f, 0.f, 0.f, 0.f}, dB = {0.f, 0.f, 0.f, 0.f};
#pragma unroll
      for (int half = 0; half < 2; ++half) {
        f16x8 bh[4];
#pragma unroll
        for (int k4 = 0; k4 < 4; ++k4)
          bh[k4] = *(const f16x8*)&h2[row][(half * 4 + k4) * 32 + lq * 8];
        dA = MFMA16(wreg[24 + half * 4 + 0], bh[0], dA);
        dB = MFMA16(wreg[24 + half * 4 + 1], bh[1], dB);
        dA = MFMA16(wreg[24 + half * 4 + 2], bh[2], dA);
        dB = MFMA16(wreg[24 + half * 4 + 3], bh[3], dB);
      }
      const uint32_t gi0 = (uint32_t)((r0 + row) * kDim + d0);
      f16x4 hx;
#pragma unroll
      for (int q = 0; q < 4; ++q) {
        const float ov    = dA[q] + dB[q] + b3q[q];
        const float eta   = bits_to_normal(draw_bits(ka, kbk, gi0 + q));
        const float score = A * (s * ov - (xv[ni][q] - x0q[ni][q]));
        const float nx    = xv[ni][q] + kDs * (ov + coef * score) + kSqrtDs * eta;
        xv[ni][q] = nx;
        hx[q] = (_Float16)nx;
      }
      *(f16x4*)&xA[row][d0] = hx;
    }
    __syncthreads();
  }

  // ---- write result (each lane owns its 8 elements) ----
#pragma unroll
  for (int ni = 0; ni < 2; ++ni) {
    const int row = (ntb + ni) * 16 + lm;
    const size_t ob = (size_t)samp * ((size_t)kObs * kDim) +
                      (size_t)(r0 + row) * kDim + d0;
    f32x4 v;
#pragma unroll
    for (int q = 0; q < 4; ++q) v[q] = xv[ni][q];
    *(f32x4*)(out + ob) = v;
  }
}

extern "C" void kernel_launch(void* const* d_in, const int* in_sizes, int n_in,
                              void* d_out, int out_size, void* d_ws, size_t ws_size,
                              hipStream_t stream) {
  const float* X0 = (const float*)d_in[0];
  const float* W1 = (const float*)d_in[1];
  const float* b1 = (const float*)d_in[2];
  const float* W2 = (const float*)d_in[3];
  const float* b2 = (const float*)d_in[4];
  const float* W3 = (const float*)d_in[5];
  const float* b3 = (const float*)d_in[6];
  _Float16* ws = (_Float16*)d_ws;   // 256 KB fragments + 2 KB key/scalar tables

  prep_weights<<<dim3(257), dim3(256), 0, stream>>>(W1, W2, W3, ws);
  sde_mfma<<<dim3(2048), dim3(512), 0, stream>>>(X0, W1, b1, b2, b3, ws,
                                                 (float*)d_out);
}

// Round 3
// 2934.441 us; speedup vs baseline: 2.5752x; 1.0484x over previous
//
#include <hip/hip_runtime.h>
#include <stdint.h>

// ---------------------------------------------------------------------------
// Fused SDE sampler, round 5: FRAGMENT-LINEAR LDS + RNG HOIST.
//   Round-4 diagnosis: on-chip loop is issue-bound (VALU 64 + MFMA 24 = 88%)
//   but SQ_LDS_BANK_CONFLICT = 3.44e8: all activation tiles had row stride
//   == 4 mod 32 words -> every B-fragment ds_read_b128 was an 8-way conflict
//   (bank group (lm+lq) mod 8).  Fix: store xA/x0A/h1/h2 as 1KB MFMA
//   fragment tiles; consumer reads are tile*1024 + lane*16 (contiguous,
//   conflict-free), producer writes are packed 8B f16x4 at
//   lane'=(mt*2+(lq>>1))*16+lm, byte (lq&1)*8 (64 distinct words, balanced).
//   RNG draws are counter-based -> hoisted (4 before L1, 4 before L3) so the
//   scheduler can fill MFMA/LDS-wait bubbles with threefry VALU ops.
//   Everything else identical to verified round 4 (weights in 128 VGPRs,
//   fused update, bit-exact JAX threefry).
// ---------------------------------------------------------------------------

#define PARTITIONABLE 1

namespace {

constexpr int   kObs    = 65536;
constexpr int   kDim    = 64;
constexpr int   kSteps  = 64;
constexpr float kDs     = 1.0f / 64.0f;
constexpr float kSqrtDs = 0.125f;

constexpr int kWeightBytes = 256 * 1024;          // 8 waves x 32 tiles x 1 KB
constexpr int kKeysOff     = kWeightBytes;        // uint32[2][64][2] = 1 KB
constexpr int kStabOff     = kKeysOff + 1024;     // f32x4[64]        = 1 KB

typedef _Float16 f16x8 __attribute__((ext_vector_type(8)));
typedef _Float16 f16x4 __attribute__((ext_vector_type(4)));
typedef float    f32x4 __attribute__((ext_vector_type(4)));

#define MFMA16(a, b, c) __builtin_amdgcn_mfma_f32_16x16x32_f16((a), (b), (c), 0, 0, 0)

__device__ __forceinline__ uint32_t rotl(uint32_t v, int r) {
  return (v << r) | (v >> (32 - r));
}

__device__ __forceinline__ void tf2x32(uint32_t k0, uint32_t k1,
                                       uint32_t& x0, uint32_t& x1) {
  uint32_t k2 = k0 ^ k1 ^ 0x1BD11BDAu;
  x0 += k0; x1 += k1;
  x0 += x1; x1 = rotl(x1, 13); x1 ^= x0;
  x0 += x1; x1 = rotl(x1, 15); x1 ^= x0;
  x0 += x1; x1 = rotl(x1, 26); x1 ^= x0;
  x0 += x1; x1 = rotl(x1,  6); x1 ^= x0;
  x0 += k1; x1 += k2 + 1u;
  x0 += x1; x1 = rotl(x1, 17); x1 ^= x0;
  x0 += x1; x1 = rotl(x1, 29); x1 ^= x0;
  x0 += x1; x1 = rotl(x1, 16); x1 ^= x0;
  x0 += x1; x1 = rotl(x1, 24); x1 ^= x0;
  x0 += k2; x1 += k0 + 2u;
  x0 += x1; x1 = rotl(x1, 13); x1 ^= x0;
  x0 += x1; x1 = rotl(x1, 15); x1 ^= x0;
  x0 += x1; x1 = rotl(x1, 26); x1 ^= x0;
  x0 += x1; x1 = rotl(x1,  6); x1 ^= x0;
  x0 += k0; x1 += k1 + 3u;
  x0 += x1; x1 = rotl(x1, 17); x1 ^= x0;
  x0 += x1; x1 = rotl(x1, 29); x1 ^= x0;
  x0 += x1; x1 = rotl(x1, 16); x1 ^= x0;
  x0 += x1; x1 = rotl(x1, 24); x1 ^= x0;
  x0 += k1; x1 += k2 + 4u;
  x0 += x1; x1 = rotl(x1, 13); x1 ^= x0;
  x0 += x1; x1 = rotl(x1, 15); x1 ^= x0;
  x0 += x1; x1 = rotl(x1, 26); x1 ^= x0;
  x0 += x1; x1 = rotl(x1,  6); x1 ^= x0;
  x0 += k2; x1 += k0 + 5u;
}

__device__ __forceinline__ void jax_split(uint32_t k0, uint32_t k1,
                                          uint32_t& a0, uint32_t& a1,
                                          uint32_t& b0, uint32_t& b1) {
#if PARTITIONABLE
  uint32_t x0 = 0u, x1 = 0u; tf2x32(k0, k1, x0, x1); a0 = x0; a1 = x1;
  uint32_t y0 = 0u, y1 = 1u; tf2x32(k0, k1, y0, y1); b0 = y0; b1 = y1;
#else
  uint32_t x0 = 0u, x1 = 2u; tf2x32(k0, k1, x0, x1);
  uint32_t y0 = 1u, y1 = 3u; tf2x32(k0, k1, y0, y1);
  a0 = x0; a1 = y0; b0 = x1; b1 = y1;
#endif
}

__device__ __forceinline__ uint32_t draw_bits(uint32_t k0, uint32_t k1, uint32_t i) {
#if PARTITIONABLE
  uint32_t x0 = 0u, x1 = i;
  tf2x32(k0, k1, x0, x1);
  return x0 ^ x1;
#else
  const uint32_t half = (uint32_t)kObs * kDim / 2;
  if (i < half) {
    uint32_t x0 = i, x1 = i + half; tf2x32(k0, k1, x0, x1); return x0;
  } else {
    uint32_t x0 = i - half, x1 = i; tf2x32(k0, k1, x0, x1); return x1;
  }
#endif
}

__device__ __forceinline__ float erfinv32(float x) {
  float w = -__logf(fmaf(-x, x, 1.0f));
  float p;
  if (w < 5.0f) {
    w = w - 2.5f;
    p =            2.81022636e-08f;
    p = fmaf(p, w, 3.43273939e-07f);
    p = fmaf(p, w, -3.5233877e-06f);
    p = fmaf(p, w, -4.39150654e-06f);
    p = fmaf(p, w, 0.00021858087f);
    p = fmaf(p, w, -0.00125372503f);
    p = fmaf(p, w, -0.00417768164f);
    p = fmaf(p, w, 0.246640727f);
    p = fmaf(p, w, 1.50140941f);
  } else {
    w = sqrtf(w) - 3.0f;
    p =            -0.000200214257f;
    p = fmaf(p, w, 0.000100950558f);
    p = fmaf(p, w, 0.00134934322f);
    p = fmaf(p, w, -0.00367342844f);
    p = fmaf(p, w, 0.00573950773f);
    p = fmaf(p, w, -0.0076224613f);
    p = fmaf(p, w, 0.00943887047f);
    p = fmaf(p, w, 1.00167406f);
    p = fmaf(p, w, 2.83297682f);
  }
  return p * x;
}

__device__ __forceinline__ float bits_to_normal(uint32_t bits) {
  const float lo = -0.99999994f;
  float f = __uint_as_float(0x3f800000u | (bits >> 9)) - 1.0f;
  float u = fmaxf(lo, fmaf(f, 2.0f, lo));
  return 1.41421356237f * erfinv32(u);
}

}  // namespace

// ---------------------------------------------------------------------------
// Weight prep: per-wave contiguous fragment tiles + RNG/step tables.
// (identical to round 4 — verified)
// ---------------------------------------------------------------------------
__global__ void prep_weights(const float* __restrict__ W1,
                             const float* __restrict__ W2,
                             const float* __restrict__ W3,
                             _Float16* __restrict__ ws) {
  const int G = blockIdx.x;
  const int t = threadIdx.x;

  if (G >= 256) {
    if (t < 2) {
      uint32_t* kout = (uint32_t*)((char*)ws + kKeysOff) + t * 128;
      uint32_t s0a, s0b, s1a, s1b;
      jax_split(0u, 1u, s0a, s0b, s1a, s1b);
      const uint32_t sk0 = t ? s1a : s0a;
      const uint32_t sk1 = t ? s1b : s0b;
      uint32_t kd0, kd1, kl0, kl1;
      jax_split(sk0, sk1, kd0, kd1, kl0, kl1);
      kout[0] = kd0; kout[1] = kd1;
      for (int n = 1; n < kSteps; ++n) {
        uint32_t na, nb, xa, xb;
        jax_split(kl0, kl1, na, nb, xa, xb);
        kl0 = na; kl1 = nb;
        kout[2 * n] = xa; kout[2 * n + 1] = xb;
      }
    }
    if (t < kSteps) {
      const float s  = (float)t * kDs;
      const float sg = 1.0f - s;
      f32x4 v;
      v[0] = s;
      v[1] = (t == 0) ? 0.0f : 1.0f / (s * sg);
      v[2] = 0.5f * (1.0f - sg * sg);
      v[3] = 0.0f;
      *(f32x4*)((char*)ws + kStabOff + t * 16) = v;
    }
    return;
  }

  const int lane = t >> 2;
  const int j0   = (t & 3) * 2;
  const int w    = G >> 5;
  const int T    = G & 31;
  const int lm   = lane & 15;
  const int kb   = (lane >> 4) << 3;

#pragma unroll
  for (int jj = 0; jj < 2; ++jj) {
    const int j = j0 + jj;
    float v;
    if (T < 8) {
      const int mt = T >> 2, kt = T & 3;
      const int col = w * 32 + mt * 16 + lm;
      const int k   = kt * 32 + kb + j;          // 0..127 : [x | x0] rows of W1
      v = W1[k * 256 + col];
    } else if (T < 24) {
      const int u = T - 8;
      const int mt = u >> 3, kt = u & 7;
      const int col = w * 32 + mt * 16 + lm;
      const int k   = kt * 32 + kb + j;
      v = W2[k * 256 + col];
    } else {
      const int kt  = T - 24;
      const int col = (w >> 1) * 16 + lm;        // L3 dim-tile = w>>1
      const int k   = kt * 32 + kb + j;
      v = W3[k * 64 + col];
    }
    ws[(size_t)G * 512 + lane * 8 + j] = (_Float16)v;
  }
}

// ---------------------------------------------------------------------------
// Main fused kernel: register weights, fragment-linear LDS, hoisted RNG.
// ---------------------------------------------------------------------------
__global__ __launch_bounds__(512, 2)
void sde_mfma(const float* __restrict__ X0g,
              const float* __restrict__ W1,
              const float* __restrict__ b1,
              const float* __restrict__ b2,
              const float* __restrict__ b3,
              const _Float16* __restrict__ ws,
              float* __restrict__ out) {
  // Fragment-tile LDS: tile(kt,nt) = 1KB; elem (k,n) -> lane'=((k&31)>>3)*16
  // + (n&15), byte lane'*16 + (k&7)*2.  Consumer b128 read = tile + l*16.
  __shared__ alignas(16) char  xAf [8 * 1024];    // kt(2) x nt(4), dims x rows
  __shared__ alignas(16) char  x0Af[8 * 1024];
  __shared__ alignas(16) char  h1f [32 * 1024];   // kt(8) x nt(4), neurons x rows
  __shared__ alignas(16) char  h2f [32 * 1024];
  __shared__ alignas(16) float bb  [832];         // b1|W1s|b2 (256 ea) | b3(64)

  const int t    = threadIdx.x;
  const int w    = t >> 6;                 // wave 0..7: neurons [32w,32w+32)
  const int l    = t & 63;
  const int lq   = l >> 4;
  const int lm   = l & 15;
  const int samp = blockIdx.x >> 10;       // 1024 blocks per sample
  const int tile = blockIdx.x & 1023;
  const int r0   = tile * 64;
  const int mt3  = w >> 1;                 // L3 dim-tile
  const int ntb  = (w & 1) * 2;            // L3 row-tile base (2 tiles)
  const int d0   = mt3 * 16 + lq * 4;      // this lane's 4 dims

  const int rb  = l * 16;                                  // consumer read off
  const int lo1 = ((lq >> 1) * 16 + lm) * 16 + (lq & 1) * 8; // producer (mt=0)
  const int kt3 = mt3 >> 1;
  const int ln3 = (((mt3 & 1) * 2 + (lq >> 1)) * 16 + lm) * 16 + (lq & 1) * 8;

  // ---- stage biases + s-row of W1 ----
  if (t < 256) {
    bb[t]       = b1[t];
    bb[256 + t] = W1[128 * 256 + t];
    bb[512 + t] = b2[t];
  } else if (t < 320) {
    bb[768 + (t - 256)] = b3[t - 256];
  }

  // ---- stage X0 tile into fragment layout: 8 dims (one lane slot) / thread ----
  {
    const int li = t >> 3;                 // row 0..63
    const int ci = (t & 7) * 8;            // dim base
    const float* p = X0g + (size_t)(r0 + li) * kDim + ci;
    const float4 a = *(const float4*)p;
    const float4 b = *(const float4*)(p + 4);
    f16x8 h;
    h[0] = (_Float16)a.x; h[1] = (_Float16)a.y;
    h[2] = (_Float16)a.z; h[3] = (_Float16)a.w;
    h[4] = (_Float16)b.x; h[5] = (_Float16)b.y;
    h[6] = (_Float16)b.z; h[7] = (_Float16)b.w;
    const int fa = ((ci >> 5) * 4 + (li >> 4)) * 1024 +
                   (((ci >> 3) & 3) * 16 + (li & 15)) * 16;
    *(f16x8*)(xAf  + fa) = h;
    *(f16x8*)(x0Af + fa) = h;
  }

  // ---- own state (f32, registers): rows (ntb+ni)*16+lm, dims d0..d0+3 ----
  float xv[2][4];
  f32x4 x0q[2];
#pragma unroll
  for (int ni = 0; ni < 2; ++ni) {
    const int row = (ntb + ni) * 16 + lm;
    x0q[ni] = *(const f32x4*)(X0g + (size_t)(r0 + row) * kDim + d0);
#pragma unroll
    for (int q = 0; q < 4; ++q) xv[ni][q] = x0q[ni][q];
  }
  const uint32_t giA = (uint32_t)((r0 + ntb * 16 + lm) * kDim + d0);
  const uint32_t giB = giA + 16u * kDim;

  // ---- preload this wave's 32 KB of weight fragments into 128 regs ----
  f16x8 wreg[32];
  {
    const char* pW = (const char*)ws + (size_t)w * 32768 + l * 16;
#pragma unroll
    for (int i = 0; i < 32; ++i)
      wreg[i] = *(const f16x8*)(pW + i * 1024);
  }

  const uint32_t* keys = (const uint32_t*)((const char*)ws + kKeysOff) + samp * 128;
  const f32x4*    stab = (const f32x4*)((const char*)ws + kStabOff);

  __syncthreads();

  for (int n = 0; n < kSteps; ++n) {
    const f32x4 st = stab[n];
    const float s = st[0], A = st[1], coef = st[2];
    const uint32_t ka = keys[2 * n], kbk = keys[2 * n + 1];

    // ---- hoisted RNG, first half (interleaves with L1/L2 MFMA) ----
    float etaA[4];
#pragma unroll
    for (int q = 0; q < 4; ++q)
      etaA[q] = bits_to_normal(draw_bits(ka, kbk, giA + q));

    // ========== layer 1: M=32 (wave's neurons), N=64, K=128 ==========
#pragma unroll
    for (int nt = 0; nt < 4; ++nt) {
      f16x8 bf[4];
      bf[0] = *(const f16x8*)(xAf  + (0 * 4 + nt) * 1024 + rb);
      bf[1] = *(const f16x8*)(xAf  + (1 * 4 + nt) * 1024 + rb);
      bf[2] = *(const f16x8*)(x0Af + (0 * 4 + nt) * 1024 + rb);
      bf[3] = *(const f16x8*)(x0Af + (1 * 4 + nt) * 1024 + rb);
#pragma unroll
      for (int mt = 0; mt < 2; ++mt) {
        f32x4 c = {0.f, 0.f, 0.f, 0.f};
#pragma unroll
        for (int kt = 0; kt < 4; ++kt)
          c = MFMA16(wreg[mt * 4 + kt], bf[kt], c);
        const int nb = w * 32 + mt * 16 + lq * 4;
        const f32x4 bq = *(const f32x4*)&bb[nb];
        const f32x4 wq = *(const f32x4*)&bb[256 + nb];
        f16x4 o;
#pragma unroll
        for (int q = 0; q < 4; ++q)
          o[q] = (_Float16)fmaxf(c[q] + fmaf(s, wq[q], bq[q]), 0.f);
        *(f16x4*)(h1f + (w * 4 + nt) * 1024 + mt * 512 + lo1) = o;
      }
    }
    __syncthreads();

    // ========== layer 2: M=32, N=64, K=256 ==========
#pragma unroll
    for (int ntp = 0; ntp < 2; ++ntp) {
      f32x4 c[2][2];
#pragma unroll
      for (int mt = 0; mt < 2; ++mt)
#pragma unroll
        for (int ni = 0; ni < 2; ++ni)
          c[mt][ni] = (f32x4){0.f, 0.f, 0.f, 0.f};
#pragma unroll
      for (int half = 0; half < 2; ++half) {
        f16x8 bh[2][4];
#pragma unroll
        for (int ni = 0; ni < 2; ++ni)
#pragma unroll
          for (int k4 = 0; k4 < 4; ++k4)
            bh[ni][k4] = *(const f16x8*)
                (h1f + ((half * 4 + k4) * 4 + ntp * 2 + ni) * 1024 + rb);
#pragma unroll
        for (int mt = 0; mt < 2; ++mt)
#pragma unroll
          for (int k4 = 0; k4 < 4; ++k4) {
            const f16x8 aW = wreg[8 + mt * 8 + half * 4 + k4];
            c[mt][0] = MFMA16(aW, bh[0][k4], c[mt][0]);
            c[mt][1] = MFMA16(aW, bh[1][k4], c[mt][1]);
          }
      }
#pragma unroll
      for (int mt = 0; mt < 2; ++mt) {
        const int nb = w * 32 + mt * 16 + lq * 4;
        const f32x4 bq = *(const f32x4*)&bb[512 + nb];
#pragma unroll
        for (int ni = 0; ni < 2; ++ni) {
          f16x4 o;
#pragma unroll
          for (int q = 0; q < 4; ++q)
            o[q] = (_Float16)fmaxf(c[mt][ni][q] + bq[q], 0.f);
          *(f16x4*)(h2f + (w * 4 + ntp * 2 + ni) * 1024 + mt * 512 + lo1) = o;
        }
      }
    }

    // ---- hoisted RNG, second half (fills the barrier/L3 window) ----
    float etaB[4];
#pragma unroll
    for (int q = 0; q < 4; ++q)
      etaB[q] = bits_to_normal(draw_bits(ka, kbk, giB + q));
    __syncthreads();

    // ========== layer 3 (dims [16*mt3,..+16)) + fused update ==========
    const f32x4 b3q = *(const f32x4*)&bb[768 + d0];
#pragma unroll
    for (int ni = 0; ni < 2; ++ni) {
      f32x4 dA = {0.f, 0.f, 0.f, 0.f}, dB = {0.f, 0.f, 0.f, 0.f};
#pragma unroll
      for (int half = 0; half < 2; ++half) {
        f16x8 bh[4];
#pragma unroll
        for (int k4 = 0; k4 < 4; ++k4)
          bh[k4] = *(const f16x8*)
              (h2f + ((half * 4 + k4) * 4 + ntb + ni) * 1024 + rb);
        dA = MFMA16(wreg[24 + half * 4 + 0], bh[0], dA);
        dB = MFMA16(wreg[24 + half * 4 + 1], bh[1], dB);
        dA = MFMA16(wreg[24 + half * 4 + 2], bh[2], dA);
        dB = MFMA16(wreg[24 + half * 4 + 3], bh[3], dB);
      }
      f16x4 hx;
#pragma unroll
      for (int q = 0; q < 4; ++q) {
        const float ov    = dA[q] + dB[q] + b3q[q];
        const float eta   = ni ? etaB[q] : etaA[q];
        const float score = A * (s * ov - (xv[ni][q] - x0q[ni][q]));
        const float nx    = xv[ni][q] + kDs * (ov + coef * score) + kSqrtDs * eta;
        xv[ni][q] = nx;
        hx[q] = (_Float16)nx;
      }
      *(f16x4*)(xAf + (kt3 * 4 + ntb + ni) * 1024 + ln3) = hx;
    }
    __syncthreads();
  }

  // ---- write result (each lane owns its 8 elements) ----
#pragma unroll
  for (int ni = 0; ni < 2; ++ni) {
    const int row = (ntb + ni) * 16 + lm;
    const size_t ob = (size_t)samp * ((size_t)kObs * kDim) +
                      (size_t)(r0 + row) * kDim + d0;
    f32x4 v;
#pragma unroll
    for (int q = 0; q < 4; ++q) v[q] = xv[ni][q];
    *(f32x4*)(out + ob) = v;
  }
}

extern "C" void kernel_launch(void* const* d_in, const int* in_sizes, int n_in,
                              void* d_out, int out_size, void* d_ws, size_t ws_size,
                              hipStream_t stream) {
  const float* X0 = (const float*)d_in[0];
  const float* W1 = (const float*)d_in[1];
  const float* b1 = (const float*)d_in[2];
  const float* W2 = (const float*)d_in[3];
  const float* b2 = (const float*)d_in[4];
  const float* W3 = (const float*)d_in[5];
  const float* b3 = (const float*)d_in[6];
  _Float16* ws = (_Float16*)d_ws;   // 256 KB fragments + 2 KB key/scalar tables

  prep_weights<<<dim3(257), dim3(256), 0, stream>>>(W1, W2, W3, ws);
  sde_mfma<<<dim3(2048), dim3(512), 0, stream>>>(X0, W1, b1, b2, b3, ws,
                                                 (float*)d_out);
}

// Round 4
// 2793.016 us; speedup vs baseline: 2.7056x; 1.0506x over previous
//
#include <hip/hip_runtime.h>
#include <stdint.h>

// ---------------------------------------------------------------------------
// Fused SDE sampler, round 6: X0-HOIST + NEXT-STEP RNG PIPELINE.
//   Round-5 diagnosis: VALU-issue-bound (VALUBusy 66%, ~80% total issue
//   occupancy, ~20% stall), occupancy pinned at 2 waves/SIMD by the 128
//   weight VGPRs.  This round cuts issue slots and fills stalls:
//   - x0 half of layer 1 (W1[64:128]·x0) is step-invariant -> hoisted out of
//     the loop (computed once per block via h1f scratch), kept as f16x4
//     pre[4][2] (16 regs, offset by 16 freed wreg tiles -> register-neutral).
//     L1: K 128->64, -16 MFMA and -8 ds_read per wave-step.
//   - etas for step n+1 computed during step n's L2/L3 regions (keys are
//     precomputed -> independent), so a stalled wave's partner always has
//     threefry VALU work to issue.
//   - update math refactored: P = kDs*coef*A precomputed per step (stab[3]),
//     5 fma-class ops/elem instead of 7.
//   Everything else identical to verified round 5 (fragment-linear LDS,
//   register weights, fused update, bit-exact JAX threefry).
// ---------------------------------------------------------------------------

#define PARTITIONABLE 1

namespace {

constexpr int   kObs    = 65536;
constexpr int   kDim    = 64;
constexpr int   kSteps  = 64;
constexpr float kDs     = 1.0f / 64.0f;
constexpr float kSqrtDs = 0.125f;

constexpr int kWeightBytes = 256 * 1024;          // 8 waves x 32 tiles x 1 KB
constexpr int kKeysOff     = kWeightBytes;        // uint32[2][64][2] = 1 KB
constexpr int kStabOff     = kKeysOff + 1024;     // f32x4[64]        = 1 KB

typedef _Float16 f16x8 __attribute__((ext_vector_type(8)));
typedef _Float16 f16x4 __attribute__((ext_vector_type(4)));
typedef float    f32x4 __attribute__((ext_vector_type(4)));

#define MFMA16(a, b, c) __builtin_amdgcn_mfma_f32_16x16x32_f16((a), (b), (c), 0, 0, 0)

__device__ __forceinline__ uint32_t rotl(uint32_t v, int r) {
  return (v << r) | (v >> (32 - r));
}

__device__ __forceinline__ void tf2x32(uint32_t k0, uint32_t k1,
                                       uint32_t& x0, uint32_t& x1) {
  uint32_t k2 = k0 ^ k1 ^ 0x1BD11BDAu;
  x0 += k0; x1 += k1;
  x0 += x1; x1 = rotl(x1, 13); x1 ^= x0;
  x0 += x1; x1 = rotl(x1, 15); x1 ^= x0;
  x0 += x1; x1 = rotl(x1, 26); x1 ^= x0;
  x0 += x1; x1 = rotl(x1,  6); x1 ^= x0;
  x0 += k1; x1 += k2 + 1u;
  x0 += x1; x1 = rotl(x1, 17); x1 ^= x0;
  x0 += x1; x1 = rotl(x1, 29); x1 ^= x0;
  x0 += x1; x1 = rotl(x1, 16); x1 ^= x0;
  x0 += x1; x1 = rotl(x1, 24); x1 ^= x0;
  x0 += k2; x1 += k0 + 2u;
  x0 += x1; x1 = rotl(x1, 13); x1 ^= x0;
  x0 += x1; x1 = rotl(x1, 15); x1 ^= x0;
  x0 += x1; x1 = rotl(x1, 26); x1 ^= x0;
  x0 += x1; x1 = rotl(x1,  6); x1 ^= x0;
  x0 += k0; x1 += k1 + 3u;
  x0 += x1; x1 = rotl(x1, 17); x1 ^= x0;
  x0 += x1; x1 = rotl(x1, 29); x1 ^= x0;
  x0 += x1; x1 = rotl(x1, 16); x1 ^= x0;
  x0 += x1; x1 = rotl(x1, 24); x1 ^= x0;
  x0 += k1; x1 += k2 + 4u;
  x0 += x1; x1 = rotl(x1, 13); x1 ^= x0;
  x0 += x1; x1 = rotl(x1, 15); x1 ^= x0;
  x0 += x1; x1 = rotl(x1, 26); x1 ^= x0;
  x0 += x1; x1 = rotl(x1,  6); x1 ^= x0;
  x0 += k2; x1 += k0 + 5u;
}

__device__ __forceinline__ void jax_split(uint32_t k0, uint32_t k1,
                                          uint32_t& a0, uint32_t& a1,
                                          uint32_t& b0, uint32_t& b1) {
#if PARTITIONABLE
  uint32_t x0 = 0u, x1 = 0u; tf2x32(k0, k1, x0, x1); a0 = x0; a1 = x1;
  uint32_t y0 = 0u, y1 = 1u; tf2x32(k0, k1, y0, y1); b0 = y0; b1 = y1;
#else
  uint32_t x0 = 0u, x1 = 2u; tf2x32(k0, k1, x0, x1);
  uint32_t y0 = 1u, y1 = 3u; tf2x32(k0, k1, y0, y1);
  a0 = x0; a1 = y0; b0 = x1; b1 = y1;
#endif
}

__device__ __forceinline__ uint32_t draw_bits(uint32_t k0, uint32_t k1, uint32_t i) {
#if PARTITIONABLE
  uint32_t x0 = 0u, x1 = i;
  tf2x32(k0, k1, x0, x1);
  return x0 ^ x1;
#else
  const uint32_t half = (uint32_t)kObs * kDim / 2;
  if (i < half) {
    uint32_t x0 = i, x1 = i + half; tf2x32(k0, k1, x0, x1); return x0;
  } else {
    uint32_t x0 = i - half, x1 = i; tf2x32(k0, k1, x0, x1); return x1;
  }
#endif
}

__device__ __forceinline__ float erfinv32(float x) {
  float w = -__logf(fmaf(-x, x, 1.0f));
  float p;
  if (w < 5.0f) {
    w = w - 2.5f;
    p =            2.81022636e-08f;
    p = fmaf(p, w, 3.43273939e-07f);
    p = fmaf(p, w, -3.5233877e-06f);
    p = fmaf(p, w, -4.39150654e-06f);
    p = fmaf(p, w, 0.00021858087f);
    p = fmaf(p, w, -0.00125372503f);
    p = fmaf(p, w, -0.00417768164f);
    p = fmaf(p, w, 0.246640727f);
    p = fmaf(p, w, 1.50140941f);
  } else {
    w = sqrtf(w) - 3.0f;
    p =            -0.000200214257f;
    p = fmaf(p, w, 0.000100950558f);
    p = fmaf(p, w, 0.00134934322f);
    p = fmaf(p, w, -0.00367342844f);
    p = fmaf(p, w, 0.00573950773f);
    p = fmaf(p, w, -0.0076224613f);
    p = fmaf(p, w, 0.00943887047f);
    p = fmaf(p, w, 1.00167406f);
    p = fmaf(p, w, 2.83297682f);
  }
  return p * x;
}

__device__ __forceinline__ float bits_to_normal(uint32_t bits) {
  const float lo = -0.99999994f;
  float f = __uint_as_float(0x3f800000u | (bits >> 9)) - 1.0f;
  float u = fmaxf(lo, fmaf(f, 2.0f, lo));
  return 1.41421356237f * erfinv32(u);
}

}  // namespace

// ---------------------------------------------------------------------------
// Weight prep: per-wave contiguous fragment tiles + RNG/step tables.
// (fragment packing identical to rounds 4/5 — verified; stab gains P=v[3])
// ---------------------------------------------------------------------------
__global__ void prep_weights(const float* __restrict__ W1,
                             const float* __restrict__ W2,
                             const float* __restrict__ W3,
                             _Float16* __restrict__ ws) {
  const int G = blockIdx.x;
  const int t = threadIdx.x;

  if (G >= 256) {
    if (t < 2) {
      uint32_t* kout = (uint32_t*)((char*)ws + kKeysOff) + t * 128;
      uint32_t s0a, s0b, s1a, s1b;
      jax_split(0u, 1u, s0a, s0b, s1a, s1b);
      const uint32_t sk0 = t ? s1a : s0a;
      const uint32_t sk1 = t ? s1b : s0b;
      uint32_t kd0, kd1, kl0, kl1;
      jax_split(sk0, sk1, kd0, kd1, kl0, kl1);
      kout[0] = kd0; kout[1] = kd1;
      for (int n = 1; n < kSteps; ++n) {
        uint32_t na, nb, xa, xb;
        jax_split(kl0, kl1, na, nb, xa, xb);
        kl0 = na; kl1 = nb;
        kout[2 * n] = xa; kout[2 * n + 1] = xb;
      }
    }
    if (t < kSteps) {
      const float s  = (float)t * kDs;
      const float sg = 1.0f - s;
      f32x4 v;
      v[0] = s;
      v[1] = (t == 0) ? 0.0f : 1.0f / (s * sg);
      v[2] = 0.5f * (1.0f - sg * sg);
      v[3] = kDs * v[2] * v[1];                    // P = ds*coef*A
      *(f32x4*)((char*)ws + kStabOff + t * 16) = v;
    }
    return;
  }

  const int lane = t >> 2;
  const int j0   = (t & 3) * 2;
  const int w    = G >> 5;
  const int T    = G & 31;
  const int lm   = lane & 15;
  const int kb   = (lane >> 4) << 3;

#pragma unroll
  for (int jj = 0; jj < 2; ++jj) {
    const int j = j0 + jj;
    float v;
    if (T < 8) {
      const int mt = T >> 2, kt = T & 3;
      const int col = w * 32 + mt * 16 + lm;
      const int k   = kt * 32 + kb + j;          // 0..127 : [x | x0] rows of W1
      v = W1[k * 256 + col];
    } else if (T < 24) {
      const int u = T - 8;
      const int mt = u >> 3, kt = u & 7;
      const int col = w * 32 + mt * 16 + lm;
      const int k   = kt * 32 + kb + j;
      v = W2[k * 256 + col];
    } else {
      const int kt  = T - 24;
      const int col = (w >> 1) * 16 + lm;        // L3 dim-tile = w>>1
      const int k   = kt * 32 + kb + j;
      v = W3[k * 64 + col];
    }
    ws[(size_t)G * 512 + lane * 8 + j] = (_Float16)v;
  }
}

// ---------------------------------------------------------------------------
// Main fused kernel: register weights, fragment LDS, hoisted x0, piped RNG.
// ---------------------------------------------------------------------------
__global__ __launch_bounds__(512, 2)
void sde_mfma(const float* __restrict__ X0g,
              const float* __restrict__ W1,
              const float* __restrict__ b1,
              const float* __restrict__ b2,
              const float* __restrict__ b3,
              const _Float16* __restrict__ ws,
              float* __restrict__ out) {
  // Fragment-tile LDS: tile(kt,nt) = 1KB; elem (k,n) -> lane'=((k&31)>>3)*16
  // + (n&15), byte lane'*16 + (k&7)*2.  Consumer b128 read = tile + l*16.
  __shared__ alignas(16) char  xAf [8 * 1024];    // kt(2) x nt(4), dims x rows
  __shared__ alignas(16) char  h1f [32 * 1024];   // kt(8) x nt(4); x0-scratch @init
  __shared__ alignas(16) char  h2f [32 * 1024];
  __shared__ alignas(16) float bb  [832];         // b1|W1s|b2 (256 ea) | b3(64)

  const int t    = threadIdx.x;
  const int w    = t >> 6;                 // wave 0..7: neurons [32w,32w+32)
  const int l    = t & 63;
  const int lq   = l >> 4;
  const int lm   = l & 15;
  const int samp = blockIdx.x >> 10;       // 1024 blocks per sample
  const int tile = blockIdx.x & 1023;
  const int r0   = tile * 64;
  const int mt3  = w >> 1;                 // L3 dim-tile
  const int ntb  = (w & 1) * 2;            // L3 row-tile base (2 tiles)
  const int d0   = mt3 * 16 + lq * 4;      // this lane's 4 dims

  const int rb  = l * 16;                                  // consumer read off
  const int lo1 = ((lq >> 1) * 16 + lm) * 16 + (lq & 1) * 8; // producer (mt=0)
  const int kt3 = mt3 >> 1;
  const int ln3 = (((mt3 & 1) * 2 + (lq >> 1)) * 16 + lm) * 16 + (lq & 1) * 8;

  // ---- stage biases + s-row of W1 ----
  if (t < 256) {
    bb[t]       = b1[t];
    bb[256 + t] = W1[128 * 256 + t];
    bb[512 + t] = b2[t];
  } else if (t < 320) {
    bb[768 + (t - 256)] = b3[t - 256];
  }

  // ---- stage X0 into fragment layout: xAf (live) + h1f (scratch for hoist) ----
  {
    const int li = t >> 3;                 // row 0..63
    const int ci = (t & 7) * 8;            // dim base
    const float* p = X0g + (size_t)(r0 + li) * kDim + ci;
    const float4 a = *(const float4*)p;
    const float4 b = *(const float4*)(p + 4);
    f16x8 h;
    h[0] = (_Float16)a.x; h[1] = (_Float16)a.y;
    h[2] = (_Float16)a.z; h[3] = (_Float16)a.w;
    h[4] = (_Float16)b.x; h[5] = (_Float16)b.y;
    h[6] = (_Float16)b.z; h[7] = (_Float16)b.w;
    const int fa = ((ci >> 5) * 4 + (li >> 4)) * 1024 +
                   (((ci >> 3) & 3) * 16 + (li & 15)) * 16;
    *(f16x8*)(xAf + fa) = h;
    *(f16x8*)(h1f + fa) = h;               // scratch copy for x0-hoist
  }

  // ---- own state (f32, registers): rows (ntb+ni)*16+lm, dims d0..d0+3 ----
  float xv[2][4];
  f32x4 x0q[2];
#pragma unroll
  for (int ni = 0; ni < 2; ++ni) {
    const int row = (ntb + ni) * 16 + lm;
    x0q[ni] = *(const f32x4*)(X0g + (size_t)(r0 + row) * kDim + d0);
#pragma unroll
    for (int q = 0; q < 4; ++q) xv[ni][q] = x0q[ni][q];
  }
  const uint32_t giA = (uint32_t)((r0 + ntb * 16 + lm) * kDim + d0);
  const uint32_t giB = giA + 16u * kDim;

  // ---- preload weight fragments: L1 x-part (4), L2 (16), L3 (8) = 112 regs;
  //      x0-part (4) transient for the hoist ----
  const char* pW = (const char*)ws + (size_t)w * 32768 + l * 16;
  f16x8 wL1[2][2], wx0[2][2], wL2[16], wL3[8];
#pragma unroll
  for (int mt = 0; mt < 2; ++mt) {
    wL1[mt][0] = *(const f16x8*)(pW + (mt * 4 + 0) * 1024);
    wL1[mt][1] = *(const f16x8*)(pW + (mt * 4 + 1) * 1024);
    wx0[mt][0] = *(const f16x8*)(pW + (mt * 4 + 2) * 1024);
    wx0[mt][1] = *(const f16x8*)(pW + (mt * 4 + 3) * 1024);
  }
#pragma unroll
  for (int i = 0; i < 16; ++i) wL2[i] = *(const f16x8*)(pW + (8 + i) * 1024);
#pragma unroll
  for (int i = 0; i < 8; ++i)  wL3[i] = *(const f16x8*)(pW + (24 + i) * 1024);

  const uint32_t* keys = (const uint32_t*)((const char*)ws + kKeysOff) + samp * 128;
  const f32x4*    stab = (const f32x4*)((const char*)ws + kStabOff);

  __syncthreads();

  // ---- hoist: pre[nt][mt] = W1[x0 rows]·x0  (step-invariant, f16x4) ----
  f16x4 pre[4][2];
#pragma unroll
  for (int nt = 0; nt < 4; ++nt) {
    const f16x8 xf0 = *(const f16x8*)(h1f + (0 * 4 + nt) * 1024 + rb);
    const f16x8 xf1 = *(const f16x8*)(h1f + (1 * 4 + nt) * 1024 + rb);
#pragma unroll
    for (int mt = 0; mt < 2; ++mt) {
      f32x4 p = {0.f, 0.f, 0.f, 0.f};
      p = MFMA16(wx0[mt][0], xf0, p);
      p = MFMA16(wx0[mt][1], xf1, p);
      f16x4 ph;
#pragma unroll
      for (int q = 0; q < 4; ++q) ph[q] = (_Float16)p[q];
      pre[nt][mt] = ph;
    }
  }
  __syncthreads();   // h1f scratch reads done before L1 overwrites it

  // ---- RNG pipeline prologue: etas for step 0 ----
  float etaA[4], etaB[4];
  {
    const uint32_t ka = keys[0], kb0 = keys[1];
#pragma unroll
    for (int q = 0; q < 4; ++q) etaA[q] = bits_to_normal(draw_bits(ka, kb0, giA + q));
#pragma unroll
    for (int q = 0; q < 4; ++q) etaB[q] = bits_to_normal(draw_bits(ka, kb0, giB + q));
  }

  for (int n = 0; n < kSteps; ++n) {
    const f32x4 st = stab[n];
    const float s = st[0], P = st[3];
    const int np = (n + 1 < kSteps) ? n + 1 : n;
    const uint32_t kna = keys[2 * np], knb = keys[2 * np + 1];

    // ========== layer 1: M=32 (wave's neurons), N=64, K=64 (x only) ======
#pragma unroll
    for (int nt = 0; nt < 4; ++nt) {
      const f16x8 bf0 = *(const f16x8*)(xAf + (0 * 4 + nt) * 1024 + rb);
      const f16x8 bf1 = *(const f16x8*)(xAf + (1 * 4 + nt) * 1024 + rb);
#pragma unroll
      for (int mt = 0; mt < 2; ++mt) {
        f32x4 c = {0.f, 0.f, 0.f, 0.f};
        c = MFMA16(wL1[mt][0], bf0, c);
        c = MFMA16(wL1[mt][1], bf1, c);
        const int nb = w * 32 + mt * 16 + lq * 4;
        const f32x4 bq = *(const f32x4*)&bb[nb];
        const f32x4 wq = *(const f32x4*)&bb[256 + nb];
        const f16x4 ph = pre[nt][mt];
        f16x4 o;
#pragma unroll
        for (int q = 0; q < 4; ++q)
          o[q] = (_Float16)fmaxf(c[q] + (float)ph[q] + fmaf(s, wq[q], bq[q]), 0.f);
        *(f16x4*)(h1f + (w * 4 + nt) * 1024 + mt * 512 + lo1) = o;
      }
    }
    __syncthreads();

    // ========== layer 2: M=32, N=64, K=256  (+ next-step RNG fill) =======
    float enA[4], enB[4];
#pragma unroll
    for (int ntp = 0; ntp < 2; ++ntp) {
      f32x4 c[2][2];
#pragma unroll
      for (int mt = 0; mt < 2; ++mt)
#pragma unroll
        for (int ni = 0; ni < 2; ++ni)
          c[mt][ni] = (f32x4){0.f, 0.f, 0.f, 0.f};
#pragma unroll
      for (int half = 0; half < 2; ++half) {
        f16x8 bh[2][4];
#pragma unroll
        for (int ni = 0; ni < 2; ++ni)
#pragma unroll
          for (int k4 = 0; k4 < 4; ++k4)
            bh[ni][k4] = *(const f16x8*)
                (h1f + ((half * 4 + k4) * 4 + ntp * 2 + ni) * 1024 + rb);
#pragma unroll
        for (int mt = 0; mt < 2; ++mt)
#pragma unroll
          for (int k4 = 0; k4 < 4; ++k4) {
            const f16x8 aW = wL2[mt * 8 + half * 4 + k4];
            c[mt][0] = MFMA16(aW, bh[0][k4], c[mt][0]);
            c[mt][1] = MFMA16(aW, bh[1][k4], c[mt][1]);
          }
      }
      // next-step RNG draws interleave with this region's MFMA/LDS waits
      if (ntp == 0) {
#pragma unroll
        for (int q = 0; q < 4; ++q)
          enA[q] = bits_to_normal(draw_bits(kna, knb, giA + q));
      } else {
#pragma unroll
        for (int q = 0; q < 4; ++q)
          enB[q] = bits_to_normal(draw_bits(kna, knb, giB + q));
      }
#pragma unroll
      for (int mt = 0; mt < 2; ++mt) {
        const int nb = w * 32 + mt * 16 + lq * 4;
        const f32x4 bq = *(const f32x4*)&bb[512 + nb];
#pragma unroll
        for (int ni = 0; ni < 2; ++ni) {
          f16x4 o;
#pragma unroll
          for (int q = 0; q < 4; ++q)
            o[q] = (_Float16)fmaxf(c[mt][ni][q] + bq[q], 0.f);
          *(f16x4*)(h2f + (w * 4 + ntp * 2 + ni) * 1024 + mt * 512 + lo1) = o;
        }
      }
    }
    __syncthreads();

    // ========== layer 3 (dims [16*mt3,..+16)) + fused update ==========
    const f32x4 b3q = *(const f32x4*)&bb[768 + d0];
#pragma unroll
    for (int ni = 0; ni < 2; ++ni) {
      f32x4 dA = {0.f, 0.f, 0.f, 0.f}, dB = {0.f, 0.f, 0.f, 0.f};
#pragma unroll
      for (int half = 0; half < 2; ++half) {
        f16x8 bh[4];
#pragma unroll
        for (int k4 = 0; k4 < 4; ++k4)
          bh[k4] = *(const f16x8*)
              (h2f + ((half * 4 + k4) * 4 + ntb + ni) * 1024 + rb);
        dA = MFMA16(wL3[half * 4 + 0], bh[0], dA);
        dB = MFMA16(wL3[half * 4 + 1], bh[1], dB);
        dA = MFMA16(wL3[half * 4 + 2], bh[2], dA);
        dB = MFMA16(wL3[half * 4 + 3], bh[3], dB);
      }
      f16x4 hx;
#pragma unroll
      for (int q = 0; q < 4; ++q) {
        const float ov  = dA[q] + dB[q] + b3q[q];
        const float eta = ni ? etaB[q] : etaA[q];
        // nx = xv + ds*ov + P*(s*ov - xv + x0q) + sqrt(ds)*eta
        const float t1  = fmaf(s, ov, x0q[ni][q] - xv[ni][q]);
        float nx = fmaf(kSqrtDs, eta, xv[ni][q]);
        nx = fmaf(kDs, ov, nx);
        nx = fmaf(P, t1, nx);
        xv[ni][q] = nx;
        hx[q] = (_Float16)nx;
      }
      *(f16x4*)(xAf + (kt3 * 4 + ntb + ni) * 1024 + ln3) = hx;
    }
    // rotate RNG pipeline
#pragma unroll
    for (int q = 0; q < 4; ++q) { etaA[q] = enA[q]; etaB[q] = enB[q]; }
    __syncthreads();
  }

  // ---- write result (each lane owns its 8 elements) ----
#pragma unroll
  for (int ni = 0; ni < 2; ++ni) {
    const int row = (ntb + ni) * 16 + lm;
    const size_t ob = (size_t)samp * ((size_t)kObs * kDim) +
                      (size_t)(r0 + row) * kDim + d0;
    f32x4 v;
#pragma unroll
    for (int q = 0; q < 4; ++q) v[q] = xv[ni][q];
    *(f32x4*)(out + ob) = v;
  }
}

extern "C" void kernel_launch(void* const* d_in, const int* in_sizes, int n_in,
                              void* d_out, int out_size, void* d_ws, size_t ws_size,
                              hipStream_t stream) {
  const float* X0 = (const float*)d_in[0];
  const float* W1 = (const float*)d_in[1];
  const float* b1 = (const float*)d_in[2];
  const float* W2 = (const float*)d_in[3];
  const float* b2 = (const float*)d_in[4];
  const float* W3 = (const float*)d_in[5];
  const float* b3 = (const float*)d_in[6];
  _Float16* ws = (_Float16*)d_ws;   // 256 KB fragments + 2 KB key/scalar tables

  prep_weights<<<dim3(257), dim3(256), 0, stream>>>(W1, W2, W3, ws);
  sde_mfma<<<dim3(2048), dim3(512), 0, stream>>>(X0, W1, b1, b2, b3, ws,
                                                 (float*)d_out);
}